// Round 1
// baseline (869.419 us; speedup 1.0000x reference)
//
#include <hip/hip_runtime.h>
#include <hip/hip_bf16.h>
#include <math.h>

// Problem constants
#define B_ 8
#define S_ 4096
#define E_ 1024
#define H_ 128
#define MIN_K 32
// d_out layout: filtered [B,S,E] | selection_mask [B,S] | expected_k [B]
#define OUT_FILT_OFF 0
#define OUT_MASK_OFF (B_*S_*E_)                 // 33554432
#define OUT_EK_OFF   (B_*S_*E_ + B_*S_)          // 33587200

// ---------------------------------------------------------------------------
// Kernel 1: fused scorer  logits[b,s] = relu(x@w1 + b1) @ w2 + b2
// block = 256 threads (4 waves). 64 tokens per block (lane = token).
// wave w handles h in [32w, 32w+32). w1/b1/w2 fetched via scalar loads
// (readfirstlane-forced uniform index) -> s_load_dwordx16, keeping the
// VALU free for the 32 FMAs per k-step.
// ---------------------------------------------------------------------------
#define K_TILE 32

__global__ __launch_bounds__(256) void scorer_kernel(
    const float* __restrict__ x, const float* __restrict__ w1,
    const float* __restrict__ b1, const float* __restrict__ w2,
    const float* __restrict__ b2, float* __restrict__ logits)
{
  __shared__ float xs[64][K_TILE + 4];   // [m][k], stride 36 floats = 144 B (16B aligned)
  __shared__ float part[4][64];

  const int tid  = threadIdx.x;
  const int wave = tid >> 6;
  const int lane = tid & 63;
  const int m0   = blockIdx.x * 64;      // global token base (0..32767)
  const int h0   = wave * 32;

  float acc[32];
#pragma unroll
  for (int j = 0; j < 32; ++j) acc[j] = 0.f;

  for (int k0 = 0; k0 < E_; k0 += K_TILE) {
    // stage x[m0..m0+63][k0..k0+31]: 512 float4, 2 per thread, coalesced
#pragma unroll
    for (int i = 0; i < 2; ++i) {
      int idx = tid + i * 256;           // 0..511
      int m   = idx >> 3;                // 0..63
      int kq  = idx & 7;                 // 0..7
      float4 v = *(const float4*)(x + (size_t)(m0 + m) * E_ + k0 + kq * 4);
      *(float4*)(&xs[m][kq * 4]) = v;
    }
    __syncthreads();

#pragma unroll
    for (int kq = 0; kq < K_TILE / 4; ++kq) {
      float4 xk4 = *(const float4*)(&xs[lane][kq * 4]);
#pragma unroll
      for (int kk = 0; kk < 4; ++kk) {
        float xk = (kk == 0) ? xk4.x : (kk == 1) ? xk4.y : (kk == 2) ? xk4.z : xk4.w;
        int wbase = __builtin_amdgcn_readfirstlane((k0 + kq * 4 + kk) * H_ + h0);
#pragma unroll
        for (int j = 0; j < 32; ++j)
          acc[j] = fmaf(xk, w1[wbase + j], acc[j]);
      }
    }
    __syncthreads();
  }

  // epilogue: relu(acc + b1) dot w2  (per-wave partial over its 32 h)
  int hb = __builtin_amdgcn_readfirstlane(h0);
  float p = 0.f;
#pragma unroll
  for (int j = 0; j < 32; ++j) {
    float h = acc[j] + b1[hb + j];
    h = h > 0.f ? h : 0.f;
    p = fmaf(h, w2[hb + j], p);
  }
  part[wave][lane] = p;
  __syncthreads();
  if (wave == 0) {
    float L = ((part[0][lane] + part[1][lane]) + (part[2][lane] + part[3][lane])) + b2[0];
    logits[m0 + lane] = L;
  }
}

// ---------------------------------------------------------------------------
// Kernel 2: per-row  expected_k, k, gumbel, softmax. grid=8, block=1024.
// f64 accumulation for the sigmoid sum (closest to exact; ref pairwise f32).
// ---------------------------------------------------------------------------
__global__ __launch_bounds__(1024) void row_kernel(
    const float* __restrict__ logits, const float* __restrict__ u,
    float* __restrict__ soft, int* __restrict__ krow, float* __restrict__ ek_out)
{
  const int b = blockIdx.x;
  const int t = threadIdx.x;
  const float* Lrow = logits + b * S_;
  const float* urow = u + b * S_;

  __shared__ double red[1024];
  __shared__ float  redf[1024];

  float z[4];
  double psig = 0.0;
  float zmax = -INFINITY;
#pragma unroll
  for (int i = 0; i < 4; ++i) {
    int j = t + i * 1024;
    float L = Lrow[j];
    float uu = urow[j];
    float g = -logf(-logf(uu));           // gumbel
    z[i] = L + g;                          // TAU = 1
    float s = 1.f / (1.f + expf(-L));
    psig += (double)s;
    zmax = fmaxf(zmax, z[i]);
  }

  red[t] = psig; redf[t] = zmax;
  __syncthreads();
  for (int s2 = 512; s2 > 0; s2 >>= 1) {
    if (t < s2) { red[t] += red[t + s2]; redf[t] = fmaxf(redf[t], redf[t + s2]); }
    __syncthreads();
  }
  __shared__ float m_sh; __shared__ double ek_sh;
  if (t == 0) { m_sh = redf[0]; ek_sh = red[0]; }
  __syncthreads();
  float m = m_sh;

  float e[4];
  double pexp = 0.0;
#pragma unroll
  for (int i = 0; i < 4; ++i) { e[i] = expf(z[i] - m); pexp += (double)e[i]; }
  red[t] = pexp;
  __syncthreads();
  for (int s2 = 512; s2 > 0; s2 >>= 1) {
    if (t < s2) red[t] += red[t + s2];
    __syncthreads();
  }
  __shared__ float den_sh;
  if (t == 0) den_sh = (float)red[0];
  __syncthreads();
  float den = den_sh;

#pragma unroll
  for (int i = 0; i < 4; ++i) soft[b * S_ + t + i * 1024] = e[i] / den;

  if (t == 0) {
    float ekf = (float)ek_sh;
    int k = (int)ekf;                     // astype(int32): trunc toward 0
    if (k < MIN_K) k = MIN_K;
    krow[b] = k;
    ek_out[b] = ekf;
  }
}

// ---------------------------------------------------------------------------
// Kernel 3: exact rank (stable argsort semantics) + selection mask.
// rank_i = #{j: s_j > s_i} + #{j<i: s_j == s_i};  hard = rank < k.
// grid = (16, 8), block = 256; j-loop is uniform -> scalar loads, L1-hot.
// ---------------------------------------------------------------------------
__global__ __launch_bounds__(256) void rank_kernel(
    const float* __restrict__ soft, const int* __restrict__ krow,
    float* __restrict__ mask_out)
{
  const int b = blockIdx.y;
  const int i = blockIdx.x * 256 + threadIdx.x;
  const float* row = soft + b * S_;
  const float si = row[i];
  const float4* row4 = (const float4*)row;
  int cnt = 0;
  for (int j4 = 0; j4 < S_ / 4; ++j4) {
    float4 v = row4[j4];
    int j = j4 * 4;
    cnt += (v.x > si) || (v.x == si && (j + 0) < i);
    cnt += (v.y > si) || (v.y == si && (j + 1) < i);
    cnt += (v.z > si) || (v.z == si && (j + 2) < i);
    cnt += (v.w > si) || (v.w == si && (j + 3) < i);
  }
  float h = (cnt < krow[b]) ? 1.f : 0.f;
  float sel = (h - si) + si;              // mirrors stop_gradient(h-s)+s forward
  mask_out[b * S_ + i] = sel;
}

// ---------------------------------------------------------------------------
// Kernel 4: filtered = x * sel.  One float4 per thread, 268 MB HBM traffic.
// ---------------------------------------------------------------------------
__global__ __launch_bounds__(256) void filter_kernel(
    const float* __restrict__ x, const float* __restrict__ mask,
    float* __restrict__ out)
{
  long long idx = (long long)blockIdx.x * 256 + threadIdx.x;  // float4 index
  float4 v = ((const float4*)x)[idx];
  int token = (int)(idx >> 8);            // E_/4 = 256 float4 per token
  float s = mask[token];
  v.x *= s; v.y *= s; v.z *= s; v.w *= s;
  ((float4*)out)[idx] = v;
}

// ---------------------------------------------------------------------------
extern "C" void kernel_launch(void* const* d_in, const int* in_sizes, int n_in,
                              void* d_out, int out_size, void* d_ws, size_t ws_size,
                              hipStream_t stream) {
  const float* x  = (const float*)d_in[0];   // [B,S,E]
  const float* w1 = (const float*)d_in[1];   // [E,H]
  const float* b1 = (const float*)d_in[2];   // [H]
  const float* w2 = (const float*)d_in[3];   // [H,1]
  const float* b2 = (const float*)d_in[4];   // [1]
  const float* u  = (const float*)d_in[5];   // [B,S]

  float* out = (float*)d_out;
  float* out_filt = out + OUT_FILT_OFF;
  float* out_mask = out + OUT_MASK_OFF;
  float* out_ek   = out + OUT_EK_OFF;

  // workspace: logits [B*S] | soft [B*S] | krow [B]
  float* ws_logits = (float*)d_ws;
  float* ws_soft   = ws_logits + B_ * S_;
  int*   ws_krow   = (int*)(ws_soft + B_ * S_);

  scorer_kernel<<<dim3(B_ * S_ / 64), dim3(256), 0, stream>>>(x, w1, b1, w2, b2, ws_logits);
  row_kernel<<<dim3(B_), dim3(1024), 0, stream>>>(ws_logits, u, ws_soft, ws_krow, out_ek);
  rank_kernel<<<dim3(S_ / 256, B_), dim3(256), 0, stream>>>(ws_soft, ws_krow, out_mask);
  filter_kernel<<<dim3(B_ * S_ * E_ / 4 / 256), dim3(256), 0, stream>>>(x, out_mask, out_filt);
}

// Round 2
// 319.104 us; speedup vs baseline: 2.7246x; 2.7246x over previous
//
#include <hip/hip_runtime.h>
#include <hip/hip_bf16.h>
#include <math.h>

// Problem constants
#define B_ 8
#define S_ 4096
#define E_ 1024
#define H_ 128
#define MIN_K 32
// d_out layout: filtered [B,S,E] | selection_mask [B,S] | expected_k [B]
#define OUT_MASK_OFF (B_*S_*E_)
#define OUT_EK_OFF   (B_*S_*E_ + B_*S_)

// workspace byte offsets (total 917,536 B)
#define LOGITS_OFF 0
#define SOFT_OFF   131072
#define CNT_OFF    262144
#define KROW_OFF   393216
#define W1T_HI_OFF 393248   // 16B aligned
#define W1T_LO_OFF 655392   // 16B aligned

typedef __attribute__((ext_vector_type(8))) short   frag8;   // 8 bf16 (4 VGPR)
typedef __attribute__((ext_vector_type(4))) float   fragc;   // 4 f32 acc
typedef __attribute__((ext_vector_type(4))) unsigned short us4;

static __device__ __forceinline__ unsigned short bf16_rne(float f) {
  unsigned u = __float_as_uint(f);
  unsigned r = u + 0x7FFF + ((u >> 16) & 1);
  return (unsigned short)(r >> 16);
}
static __device__ __forceinline__ float bf16_to_f32(unsigned short h) {
  return __uint_as_float(((unsigned)h) << 16);
}

// ---------------------------------------------------------------------------
// Prep: w1 [E][H] f32  ->  w1t_hi/w1t_lo [H][E] bf16 (transposed, k-contiguous)
// ---------------------------------------------------------------------------
__global__ __launch_bounds__(256) void prep_w_kernel(
    const float* __restrict__ w1,
    unsigned short* __restrict__ w1t_hi, unsigned short* __restrict__ w1t_lo)
{
  int id = blockIdx.x * 256 + threadIdx.x;       // 0..32767
  int k  = id >> 5;                               // 0..1023
  int n4 = id & 31;                               // 0..31
  float4 w = *(const float4*)(w1 + k * H_ + n4 * 4);
#pragma unroll
  for (int e = 0; e < 4; ++e) {
    float f = (e == 0) ? w.x : (e == 1) ? w.y : (e == 2) ? w.z : w.w;
    unsigned short hi = bf16_rne(f);
    unsigned short lo = bf16_rne(f - bf16_to_f32(hi));
    int n = n4 * 4 + e;
    w1t_hi[n * E_ + k] = hi;
    w1t_lo[n * E_ + k] = lo;
  }
}

// ---------------------------------------------------------------------------
// Scorer: logits = relu(x@w1 + b1)@w2 + b2 via split-bf16 MFMA (3 products).
// Block 256 thr (4 waves). Tile M=64, N=128, KT=32. Wave w: n in [32w,32w+32)
// (2 n-tiles of 16), 4 m-tiles of 16. A from LDS (b128 frags), B direct from
// global w1t (L2-hot, 16B contiguous per lane). Grid 512.
// ---------------------------------------------------------------------------
#define KT 32
#define XS_STRIDE 40   // bf16 units; 80 B = 5*16B -> frag reads 16B-aligned, 2-way banks (free)

__global__ __launch_bounds__(256) void scorer_kernel(
    const float* __restrict__ x,
    const unsigned short* __restrict__ w1t_hi,
    const unsigned short* __restrict__ w1t_lo,
    const float* __restrict__ b1, const float* __restrict__ w2,
    const float* __restrict__ b2, float* __restrict__ logits)
{
  __shared__ unsigned short xs_hi[64 * XS_STRIDE];
  __shared__ unsigned short xs_lo[64 * XS_STRIDE];
  __shared__ float part[4][64];

  const int tid  = threadIdx.x;
  const int wave = tid >> 6;
  const int lane = tid & 63;
  const int l15  = lane & 15;
  const int quad = lane >> 4;
  const int m0   = blockIdx.x * 64;
  const int nbase = wave * 32;

  fragc acc[4][2];
#pragma unroll
  for (int mt = 0; mt < 4; ++mt)
#pragma unroll
    for (int nt = 0; nt < 2; ++nt)
      acc[mt][nt] = (fragc)(0.f);

  // staging indices: idx = tid + i*256 (0..511): m = idx>>3, kq = idx&7
  const int sm0 = tid >> 3, skq0 = tid & 7;
  const int sm1 = (tid + 256) >> 3, skq1 = (tid + 256) & 7;

  // prefetch tile k0=0
  float4 p0 = *(const float4*)(x + (size_t)(m0 + sm0) * E_ + skq0 * 4);
  float4 p1 = *(const float4*)(x + (size_t)(m0 + sm1) * E_ + skq1 * 4);

  for (int k0 = 0; k0 < E_; k0 += KT) {
    __syncthreads();   // previous tile's reads complete
    // convert + store staged tile
    {
      us4 h4, l4;
      float fv[4] = {p0.x, p0.y, p0.z, p0.w};
#pragma unroll
      for (int e = 0; e < 4; ++e) {
        unsigned short hi = bf16_rne(fv[e]);
        h4[e] = hi; l4[e] = bf16_rne(fv[e] - bf16_to_f32(hi));
      }
      *(us4*)&xs_hi[sm0 * XS_STRIDE + skq0 * 4] = h4;
      *(us4*)&xs_lo[sm0 * XS_STRIDE + skq0 * 4] = l4;
      float gv[4] = {p1.x, p1.y, p1.z, p1.w};
#pragma unroll
      for (int e = 0; e < 4; ++e) {
        unsigned short hi = bf16_rne(gv[e]);
        h4[e] = hi; l4[e] = bf16_rne(gv[e] - bf16_to_f32(hi));
      }
      *(us4*)&xs_hi[sm1 * XS_STRIDE + skq1 * 4] = h4;
      *(us4*)&xs_lo[sm1 * XS_STRIDE + skq1 * 4] = l4;
    }
    __syncthreads();

    // prefetch next tile while computing this one
    if (k0 + KT < E_) {
      p0 = *(const float4*)(x + (size_t)(m0 + sm0) * E_ + (k0 + KT) + skq0 * 4);
      p1 = *(const float4*)(x + (size_t)(m0 + sm1) * E_ + (k0 + KT) + skq1 * 4);
    }

    // A fragments from LDS
    frag8 ah[4], al[4];
#pragma unroll
    for (int mt = 0; mt < 4; ++mt) {
      int a = (mt * 16 + l15) * XS_STRIDE + quad * 8;
      ah[mt] = *(const frag8*)&xs_hi[a];
      al[mt] = *(const frag8*)&xs_lo[a];
    }
    // B fragments direct from global (L2-hot)
    frag8 bh[2], bl[2];
#pragma unroll
    for (int nt = 0; nt < 2; ++nt) {
      int n = nbase + nt * 16 + l15;
      size_t off = (size_t)n * E_ + k0 + quad * 8;
      bh[nt] = *(const frag8*)(w1t_hi + off);
      bl[nt] = *(const frag8*)(w1t_lo + off);
    }
#pragma unroll
    for (int mt = 0; mt < 4; ++mt)
#pragma unroll
      for (int nt = 0; nt < 2; ++nt) {
        acc[mt][nt] = __builtin_amdgcn_mfma_f32_16x16x32_bf16(ah[mt], bh[nt], acc[mt][nt], 0, 0, 0);
        acc[mt][nt] = __builtin_amdgcn_mfma_f32_16x16x32_bf16(ah[mt], bl[nt], acc[mt][nt], 0, 0, 0);
        acc[mt][nt] = __builtin_amdgcn_mfma_f32_16x16x32_bf16(al[mt], bh[nt], acc[mt][nt], 0, 0, 0);
      }
  }

  // Epilogue: h = relu(acc + b1[n]); partial logit = h*w2[n]; reduce over n.
  float b1v[2], w2v[2];
#pragma unroll
  for (int nt = 0; nt < 2; ++nt) {
    int n = nbase + nt * 16 + l15;
    b1v[nt] = b1[n]; w2v[nt] = w2[n];
  }
  float v[4][4];
#pragma unroll
  for (int mt = 0; mt < 4; ++mt)
#pragma unroll
    for (int reg = 0; reg < 4; ++reg) {
      float p = 0.f;
#pragma unroll
      for (int nt = 0; nt < 2; ++nt) {
        float h = acc[mt][nt][reg] + b1v[nt];
        h = h > 0.f ? h : 0.f;
        p = fmaf(h, w2v[nt], p);
      }
      v[mt][reg] = p;
    }
  // butterfly over the 16-lane (n) group; quad preserved (masks < 16)
#pragma unroll
  for (int mask = 1; mask < 16; mask <<= 1)
#pragma unroll
    for (int mt = 0; mt < 4; ++mt)
#pragma unroll
      for (int reg = 0; reg < 4; ++reg)
        v[mt][reg] += __shfl_xor(v[mt][reg], mask);

  if (l15 == 0) {
#pragma unroll
    for (int mt = 0; mt < 4; ++mt)
#pragma unroll
      for (int reg = 0; reg < 4; ++reg)
        part[wave][mt * 16 + quad * 4 + reg] = v[mt][reg];
  }
  __syncthreads();
  if (tid < 64)
    logits[m0 + tid] = ((part[0][tid] + part[1][tid]) + (part[2][tid] + part[3][tid])) + b2[0];
}

// ---------------------------------------------------------------------------
// Row kernel: expected_k, k, gumbel, softmax. grid=8, block=1024. (unchanged)
// ---------------------------------------------------------------------------
__global__ __launch_bounds__(1024) void row_kernel(
    const float* __restrict__ logits, const float* __restrict__ u,
    float* __restrict__ soft, int* __restrict__ krow, float* __restrict__ ek_out)
{
  const int b = blockIdx.x;
  const int t = threadIdx.x;
  const float* Lrow = logits + b * S_;
  const float* urow = u + b * S_;

  __shared__ double red[1024];
  __shared__ float  redf[1024];

  float z[4];
  double psig = 0.0;
  float zmax = -INFINITY;
#pragma unroll
  for (int i = 0; i < 4; ++i) {
    int j = t + i * 1024;
    float L = Lrow[j];
    float g = -logf(-logf(urow[j]));
    z[i] = L + g;
    psig += (double)(1.f / (1.f + expf(-L)));
    zmax = fmaxf(zmax, z[i]);
  }
  red[t] = psig; redf[t] = zmax;
  __syncthreads();
  for (int s2 = 512; s2 > 0; s2 >>= 1) {
    if (t < s2) { red[t] += red[t + s2]; redf[t] = fmaxf(redf[t], redf[t + s2]); }
    __syncthreads();
  }
  __shared__ float m_sh; __shared__ double ek_sh;
  if (t == 0) { m_sh = redf[0]; ek_sh = red[0]; }
  __syncthreads();
  float m = m_sh;

  float e[4];
  double pexp = 0.0;
#pragma unroll
  for (int i = 0; i < 4; ++i) { e[i] = expf(z[i] - m); pexp += (double)e[i]; }
  red[t] = pexp;
  __syncthreads();
  for (int s2 = 512; s2 > 0; s2 >>= 1) {
    if (t < s2) red[t] += red[t + s2];
    __syncthreads();
  }
  __shared__ float den_sh;
  if (t == 0) den_sh = (float)red[0];
  __syncthreads();
  float den = den_sh;
#pragma unroll
  for (int i = 0; i < 4; ++i) soft[b * S_ + t + i * 1024] = e[i] / den;

  if (t == 0) {
    float ekf = (float)ek_sh;
    int k = (int)ekf;
    if (k < MIN_K) k = MIN_K;
    krow[b] = k;
    ek_out[b] = ekf;
  }
}

// ---------------------------------------------------------------------------
// Rank partial: grid (16 i-chunks, 4 j-chunks, 8 rows). Integer atomicAdd
// (deterministic). j-chunk staged in LDS; all lanes read same addr (broadcast).
// ---------------------------------------------------------------------------
__global__ __launch_bounds__(256) void rank_kernel(
    const float* __restrict__ soft, int* __restrict__ counts)
{
  __shared__ float4 sjs[256];
  const int b  = blockIdx.z;
  const int ic = blockIdx.x;
  const int jc = blockIdx.y;
  const int tid = threadIdx.x;
  const float* row = soft + b * S_;

  sjs[tid] = ((const float4*)row)[jc * 256 + tid];
  const int i = ic * 256 + tid;
  const float si = row[i];
  __syncthreads();

  int cnt = 0;
  const int jbase = jc * 1024;
  for (int j4 = 0; j4 < 256; ++j4) {
    float4 vv = sjs[j4];
    int j = jbase + j4 * 4;
    cnt += (vv.x > si) || (vv.x == si && (j + 0) < i);
    cnt += (vv.y > si) || (vv.y == si && (j + 1) < i);
    cnt += (vv.z > si) || (vv.z == si && (j + 2) < i);
    cnt += (vv.w > si) || (vv.w == si && (j + 3) < i);
  }
  atomicAdd(&counts[b * S_ + i], cnt);
}

// ---------------------------------------------------------------------------
// Filter + mask finalize: one block per token (1024 floats). Uniform scalar
// loads of cnt/k/soft; thread 0 writes selection_mask.
// ---------------------------------------------------------------------------
__global__ __launch_bounds__(256) void filter_kernel(
    const float* __restrict__ x, const float* __restrict__ soft,
    const int* __restrict__ counts, const int* __restrict__ krow,
    float* __restrict__ out, float* __restrict__ mask_out)
{
  const int token = blockIdx.x;           // 0..32767
  const int b = token >> 12;              // S_=4096
  const float s = soft[token];
  const float h = (counts[token] < krow[b]) ? 1.f : 0.f;
  const float sel = (h - s) + s;

  size_t base = (size_t)token * (E_ / 4) + threadIdx.x;
  float4 v = ((const float4*)x)[base];
  v.x *= sel; v.y *= sel; v.z *= sel; v.w *= sel;
  ((float4*)out)[base] = v;
  if (threadIdx.x == 0) mask_out[token] = sel;
}

// ---------------------------------------------------------------------------
extern "C" void kernel_launch(void* const* d_in, const int* in_sizes, int n_in,
                              void* d_out, int out_size, void* d_ws, size_t ws_size,
                              hipStream_t stream) {
  const float* x  = (const float*)d_in[0];
  const float* w1 = (const float*)d_in[1];
  const float* b1 = (const float*)d_in[2];
  const float* w2 = (const float*)d_in[3];
  const float* b2 = (const float*)d_in[4];
  const float* u  = (const float*)d_in[5];

  float* out = (float*)d_out;
  float* out_filt = out;
  float* out_mask = out + OUT_MASK_OFF;
  float* out_ek   = out + OUT_EK_OFF;

  char* ws = (char*)d_ws;
  float*          ws_logits = (float*)(ws + LOGITS_OFF);
  float*          ws_soft   = (float*)(ws + SOFT_OFF);
  int*            ws_cnt    = (int*)(ws + CNT_OFF);
  int*            ws_krow   = (int*)(ws + KROW_OFF);
  unsigned short* ws_w1thi  = (unsigned short*)(ws + W1T_HI_OFF);
  unsigned short* ws_w1tlo  = (unsigned short*)(ws + W1T_LO_OFF);

  hipMemsetAsync(ws_cnt, 0, B_ * S_ * sizeof(int), stream);
  prep_w_kernel<<<dim3(128), dim3(256), 0, stream>>>(w1, ws_w1thi, ws_w1tlo);
  scorer_kernel<<<dim3(B_ * S_ / 64), dim3(256), 0, stream>>>(
      x, ws_w1thi, ws_w1tlo, b1, w2, b2, ws_logits);
  row_kernel<<<dim3(B_), dim3(1024), 0, stream>>>(ws_logits, u, ws_soft, ws_krow, out_ek);
  rank_kernel<<<dim3(16, 4, 8), dim3(256), 0, stream>>>(ws_soft, ws_cnt);
  filter_kernel<<<dim3(B_ * S_), dim3(256), 0, stream>>>(
      x, ws_soft, ws_cnt, ws_krow, out_filt, out_mask);
}